// Round 5
// baseline (90.847 us; speedup 1.0000x reference)
//
#include <hip/hip_runtime.h>
#include <math.h>

#define NPAIRS  262144
#define D4      32                  // 128 floats = 32 float4 per row
#define TPB     256
#define NBLK    2048
#define GPB     (TPB / 32)          // 8 groups per block
#define NGROUPS (NBLK * GPB)        // 16384
#define PPG     (NPAIRS / NGROUPS)  // 16 pairs per group per list

// 32-lane group per pair; lane l holds float4 #l of each row (512B coalesced).
//
// R5: batch 4 pairs per iteration WITH register budget to match
// (__launch_bounds__(256,4) -> VGPR cap 128, 16 waves/CU). 8 float4 gathers
// (32 VGPRs) issued back-to-back per batch -> ~4 KB in flight per wave,
// covering the ~225cy L2-hit latency (need ~12.6 KB/CU; we have ~64 KB/CU).
// R2's x4 unroll was neutral because at VGPR=32 the loads couldn't stay in
// flight; R4's VGPR=24 had the same problem with 1 pair/iter.
//
// Indices: each group's 16 pairs (32 ints = 128 B/list) preloaded with one
// coalesced dword/lane load; per-pair (i,j) via __shfl broadcast (ds ops,
// no memory latency). Consecutive pos pairs share i (np.nonzero runs ~63)
// -> a-row hits L1.
//
// Pos: separable -> per-lane accumulate, ONE butterfly at the end.
// Neg: 4 independent butterfly chains interleaved (pipelined on DS pipe).
// Reduction: per-block partials + finalize kernel (R2/R3 lesson: same-address
// atomicAdd from 2048 blocks serializes at TCC, ~25us tail).
__global__ __launch_bounds__(TPB, 4) void pair_kernel(
    const float* __restrict__ X,
    const int*   __restrict__ pos_i,
    const int*   __restrict__ neg_i,
    const float* __restrict__ h_bias,
    float* __restrict__ partials)
{
    const int lane  = threadIdx.x & 31;
    const int group = threadIdx.x >> 5;
    const int gid   = (blockIdx.x * TPB + threadIdx.x) >> 5;

    const float4* __restrict__ X4 = (const float4*)X;

    // numerically stable softplus(h_bias)
    const float hb   = h_bias[0];
    const float bias = fmaxf(hb, 0.0f) + log1pf(expf(-fabsf(hb)));

    // Preload this group's 16 pairs from each list (one dword per lane).
    const int pidx = pos_i[gid * 32 + lane];
    const int nidx = neg_i[gid * 32 + lane];

    // ---------------- positive pairs: separable, batch 4 ------------------
    float posAcc = 0.0f;
    #pragma unroll
    for (int t = 0; t < PPG; t += 4) {
        const int i0 = __shfl(pidx, 2 * t,     32), j0 = __shfl(pidx, 2 * t + 1, 32);
        const int i1 = __shfl(pidx, 2 * t + 2, 32), j1 = __shfl(pidx, 2 * t + 3, 32);
        const int i2 = __shfl(pidx, 2 * t + 4, 32), j2 = __shfl(pidx, 2 * t + 5, 32);
        const int i3 = __shfl(pidx, 2 * t + 6, 32), j3 = __shfl(pidx, 2 * t + 7, 32);
        const float4 a0 = X4[i0 * D4 + lane], b0 = X4[j0 * D4 + lane];
        const float4 a1 = X4[i1 * D4 + lane], b1 = X4[j1 * D4 + lane];
        const float4 a2 = X4[i2 * D4 + lane], b2 = X4[j2 * D4 + lane];
        const float4 a3 = X4[i3 * D4 + lane], b3 = X4[j3 * D4 + lane];
        float d;
        d = a0.x - b0.x; posAcc = fmaf(d, d, posAcc);
        d = a0.y - b0.y; posAcc = fmaf(d, d, posAcc);
        d = a0.z - b0.z; posAcc = fmaf(d, d, posAcc);
        d = a0.w - b0.w; posAcc = fmaf(d, d, posAcc);
        d = a1.x - b1.x; posAcc = fmaf(d, d, posAcc);
        d = a1.y - b1.y; posAcc = fmaf(d, d, posAcc);
        d = a1.z - b1.z; posAcc = fmaf(d, d, posAcc);
        d = a1.w - b1.w; posAcc = fmaf(d, d, posAcc);
        d = a2.x - b2.x; posAcc = fmaf(d, d, posAcc);
        d = a2.y - b2.y; posAcc = fmaf(d, d, posAcc);
        d = a2.z - b2.z; posAcc = fmaf(d, d, posAcc);
        d = a2.w - b2.w; posAcc = fmaf(d, d, posAcc);
        d = a3.x - b3.x; posAcc = fmaf(d, d, posAcc);
        d = a3.y - b3.y; posAcc = fmaf(d, d, posAcc);
        d = a3.z - b3.z; posAcc = fmaf(d, d, posAcc);
        d = a3.w - b3.w; posAcc = fmaf(d, d, posAcc);
    }

    // ---------------- negative pairs: batch 4, interleaved butterflies -----
    float negAcc = 0.0f;
    #pragma unroll
    for (int t = 0; t < PPG; t += 4) {
        const int i0 = __shfl(nidx, 2 * t,     32), j0 = __shfl(nidx, 2 * t + 1, 32);
        const int i1 = __shfl(nidx, 2 * t + 2, 32), j1 = __shfl(nidx, 2 * t + 3, 32);
        const int i2 = __shfl(nidx, 2 * t + 4, 32), j2 = __shfl(nidx, 2 * t + 5, 32);
        const int i3 = __shfl(nidx, 2 * t + 6, 32), j3 = __shfl(nidx, 2 * t + 7, 32);
        const float4 a0 = X4[i0 * D4 + lane], b0 = X4[j0 * D4 + lane];
        const float4 a1 = X4[i1 * D4 + lane], b1 = X4[j1 * D4 + lane];
        const float4 a2 = X4[i2 * D4 + lane], b2 = X4[j2 * D4 + lane];
        const float4 a3 = X4[i3 * D4 + lane], b3 = X4[j3 * D4 + lane];
        float d;
        float s0 = 0.f, s1 = 0.f, s2 = 0.f, s3 = 0.f;
        d = a0.x - b0.x; s0 = fmaf(d, d, s0);
        d = a0.y - b0.y; s0 = fmaf(d, d, s0);
        d = a0.z - b0.z; s0 = fmaf(d, d, s0);
        d = a0.w - b0.w; s0 = fmaf(d, d, s0);
        d = a1.x - b1.x; s1 = fmaf(d, d, s1);
        d = a1.y - b1.y; s1 = fmaf(d, d, s1);
        d = a1.z - b1.z; s1 = fmaf(d, d, s1);
        d = a1.w - b1.w; s1 = fmaf(d, d, s1);
        d = a2.x - b2.x; s2 = fmaf(d, d, s2);
        d = a2.y - b2.y; s2 = fmaf(d, d, s2);
        d = a2.z - b2.z; s2 = fmaf(d, d, s2);
        d = a2.w - b2.w; s2 = fmaf(d, d, s2);
        d = a3.x - b3.x; s3 = fmaf(d, d, s3);
        d = a3.y - b3.y; s3 = fmaf(d, d, s3);
        d = a3.z - b3.z; s3 = fmaf(d, d, s3);
        d = a3.w - b3.w; s3 = fmaf(d, d, s3);
        #pragma unroll
        for (int m = 16; m > 0; m >>= 1) {
            s0 += __shfl_xor(s0, m, 32);
            s1 += __shfl_xor(s1, m, 32);
            s2 += __shfl_xor(s2, m, 32);
            s3 += __shfl_xor(s3, m, 32);
        }
        float r;
        r = fmaxf(bias - sqrtf(s0), 0.f); negAcc = fmaf(r, r, negAcc);
        r = fmaxf(bias - sqrtf(s1), 0.f); negAcc = fmaf(r, r, negAcc);
        r = fmaxf(bias - sqrtf(s2), 0.f); negAcc = fmaf(r, r, negAcc);
        r = fmaxf(bias - sqrtf(s3), 0.f); negAcc = fmaf(r, r, negAcc);
    }
    // negAcc is group-uniform after the butterflies.

    // reduce posAcc across the 32-lane group
    #pragma unroll
    for (int m = 16; m > 0; m >>= 1) posAcc += __shfl_xor(posAcc, m, 32);

    __shared__ float sp[GPB], sn[GPB];
    if (lane == 0) { sp[group] = posAcc; sn[group] = negAcc; }
    __syncthreads();
    if (threadIdx.x == 0) {
        float P = 0.f, Nn = 0.f;
        #pragma unroll
        for (int g = 0; g < GPB; ++g) { P += sp[g]; Nn += sn[g]; }
        partials[2 * blockIdx.x]     = P;
        partials[2 * blockIdx.x + 1] = Nn;
    }
}

__global__ __launch_bounds__(TPB) void finalize_kernel(
    const float* __restrict__ partials, float* __restrict__ out)
{
    __shared__ float sp[TPB], sn[TPB];
    float p = 0.0f, n = 0.0f;
    for (int b = threadIdx.x; b < NBLK; b += TPB) {
        p += partials[2 * b];
        n += partials[2 * b + 1];
    }
    sp[threadIdx.x] = p; sn[threadIdx.x] = n;
    __syncthreads();
    for (int s = TPB / 2; s > 0; s >>= 1) {
        if ((int)threadIdx.x < s) {
            sp[threadIdx.x] += sp[threadIdx.x + s];
            sn[threadIdx.x] += sn[threadIdx.x + s];
        }
        __syncthreads();
    }
    if (threadIdx.x == 0) {
        out[0] = 0.5f * sp[0] / (float)NPAIRS;
        out[1] = 0.5f * sn[0] / (float)NPAIRS;
    }
}

extern "C" void kernel_launch(void* const* d_in, const int* in_sizes, int n_in,
                              void* d_out, int out_size, void* d_ws, size_t ws_size,
                              hipStream_t stream) {
    const float* X      = (const float*)d_in[0];
    // d_in[1] = scores (unused), d_in[3] = labels (unused)
    const float* h_bias = (const float*)d_in[2];
    const int*   pos_i  = (const int*)d_in[4];
    const int*   neg_i  = (const int*)d_in[5];
    float*       out    = (float*)d_out;
    float*       partials = (float*)d_ws;

    pair_kernel<<<NBLK, TPB, 0, stream>>>(X, pos_i, neg_i, h_bias, partials);
    finalize_kernel<<<1, TPB, 0, stream>>>(partials, out);
}